// Round 4
// baseline (194.521 us; speedup 1.0000x reference)
//
#include <hip/hip_runtime.h>

// MechanicsFunctionsMultiBlock: per-element Neo-Hookean energy Hessian (2D, NEN=3, NQP=1).
// Closed-form Hessian:
//   H[n,c,m,d] = vol * ( mu_eff * (c==d) * dot(G[n],G[m])
//                      + (mu_eff - lam*logJ) * P[n,d]*P[m,c]
//                      + lam * P[n,c]*P[m,d] )
// with F = I + gradU, P = G * F^{-1}, mu_eff = mu*(1 + 0.01*state).
//
// R4: same as R3 but nontemporal store uses a clang native vector type
// (ext_vector_type) — __builtin_nontemporal_store rejects HIP_vector_type.

constexpr int E_CNT  = 800000;
constexpr int HALF_E = 400000;

typedef float v2f __attribute__((ext_vector_type(2)));

__global__ __launch_bounds__(256) void zero_flags_kernel(uint4* __restrict__ flag4) {
  int i = blockIdx.x * blockDim.x + threadIdx.x;
  if (i < E_CNT / 16) flag4[i] = make_uint4(0, 0, 0, 0);
}

__global__ __launch_bounds__(256) void mark_b1_kernel(
    const int* __restrict__ b1, unsigned char* __restrict__ flag) {
  int i = blockIdx.x * blockDim.x + threadIdx.x;
  if (i < HALF_E) flag[b1[i]] = 1;  // block1: lam=2.0, mu=1.0
}

__global__ __launch_bounds__(256) void hess_kernel(
    const float* __restrict__ U, const float* __restrict__ state,
    const int* __restrict__ conns, const float* __restrict__ grads,
    const float* __restrict__ vols, const unsigned char* __restrict__ flag,
    float* __restrict__ out) {
  __shared__ float lds[128 * 37];  // 18944 B -> LDS no longer the occupancy cap
  const int tid = threadIdx.x;
  const int e = blockIdx.x * 256 + tid;  // E = 3125*256 exactly, no tail

  const bool b  = flag[e] != 0;
  const float lam = b ? 2.0f : 1.0f;
  const float mu  = b ? 1.0f : 0.5f;

  const int n0 = conns[3 * e + 0];
  const int n1 = conns[3 * e + 1];
  const int n2 = conns[3 * e + 2];
  const float2 d0 = *(const float2*)(U + 2 * n0);
  const float2 d1 = *(const float2*)(U + 2 * n1);
  const float2 d2 = *(const float2*)(U + 2 * n2);
  const float2* gp = (const float2*)(grads + 6 * e);
  const float2 g0 = gp[0], g1 = gp[1], g2 = gp[2];

  // gradU[c][d] = sum_n D[n][c] * G[n][d]
  const float gu00 = d0.x * g0.x + d1.x * g1.x + d2.x * g2.x;
  const float gu01 = d0.x * g0.y + d1.x * g1.y + d2.x * g2.y;
  const float gu10 = d0.y * g0.x + d1.y * g1.x + d2.y * g2.x;
  const float gu11 = d0.y * g0.y + d1.y * g1.y + d2.y * g2.y;

  const float F00 = 1.0f + gu00, F01 = gu01, F10 = gu10, F11 = 1.0f + gu11;
  const float J    = F00 * F11 - F01 * F10;
  const float logJ = logf(J);
  const float rJ   = 1.0f / J;
  const float Fi00 =  F11 * rJ, Fi01 = -F01 * rJ;
  const float Fi10 = -F10 * rJ, Fi11 =  F00 * rJ;

  // P[n][c] = G[n][0]*Finv[0][c] + G[n][1]*Finv[1][c]
  float P[3][2];
  P[0][0] = g0.x * Fi00 + g0.y * Fi10;  P[0][1] = g0.x * Fi01 + g0.y * Fi11;
  P[1][0] = g1.x * Fi00 + g1.y * Fi10;  P[1][1] = g1.x * Fi01 + g1.y * Fi11;
  P[2][0] = g2.x * Fi00 + g2.y * Fi10;  P[2][1] = g2.x * Fi01 + g2.y * Fi11;

  const float gx[3] = {g0.x, g1.x, g2.x};
  const float gy[3] = {g0.y, g1.y, g2.y};

  const float mu_eff = mu * (1.0f + 0.01f * state[e]);
  const float c2     = mu_eff - lam * logJ;
  const float vol    = vols[e];

  float h[36];
#pragma unroll
  for (int n = 0; n < 3; ++n) {
#pragma unroll
    for (int m = 0; m < 3; ++m) {
      const float dg = gx[n] * gx[m] + gy[n] * gy[m];
#pragma unroll
      for (int c = 0; c < 2; ++c) {
#pragma unroll
        for (int d = 0; d < 2; ++d) {
          float v = c2 * P[n][d] * P[m][c] + lam * P[n][c] * P[m][d];
          if (c == d) v += mu_eff * dg;
          h[n * 12 + c * 6 + m * 2 + d] = vol * v;
        }
      }
    }
  }

  // Two-phase flush: phase p stages elements [p*128, p*128+128) through LDS
  // (stride 37 -> 2-way-max bank aliasing = free), then ALL threads write
  // 4608 contiguous floats as coalesced nontemporal float2s.
  const size_t blk_base = 36 * (size_t)(blockIdx.x * 256);
#pragma unroll
  for (int p = 0; p < 2; ++p) {
    if (p) __syncthreads();
    if ((tid >> 7) == p) {           // wave-uniform: waves 0,1 vs 2,3
      float* hl = lds + (tid & 127) * 37;
#pragma unroll
      for (int q = 0; q < 36; ++q) hl[q] = h[q];
    }
    __syncthreads();
    float* ob = out + blk_base + p * 4608;
#pragma unroll
    for (int i = 0; i < 9; ++i) {
      const int g = tid + i * 256;           // float2 index within phase
      const int f = 2 * g;                   // flat float index
      const int el = f / 36;                 // element within phase
      const int j  = f - 36 * el;            // even, so j+1 stays in-element
      v2f v;
      v.x = lds[el * 37 + j];
      v.y = lds[el * 37 + j + 1];
      __builtin_nontemporal_store(v, (v2f*)(ob + f));
    }
  }
}

extern "C" void kernel_launch(void* const* d_in, const int* in_sizes, int n_in,
                              void* d_out, int out_size, void* d_ws, size_t ws_size,
                              hipStream_t stream) {
  const float* U     = (const float*)d_in[0];
  // d_in[1] = coords   (unused by the Hessian)
  const float* state = (const float*)d_in[2];
  const int*   conns = (const int*)d_in[3];
  // d_in[4] = shapes   (unused by the Hessian)
  const float* grads = (const float*)d_in[5];
  const float* vols  = (const float*)d_in[6];
  // d_in[7] = blocks0  (flag defaults to 0)
  const int*   b1    = (const int*)d_in[8];
  float* out = (float*)d_out;
  unsigned char* flag = (unsigned char*)d_ws;  // E bytes of scratch

  zero_flags_kernel<<<(E_CNT / 16 + 255) / 256, 256, 0, stream>>>((uint4*)flag);
  mark_b1_kernel<<<(HALF_E + 255) / 256, 256, 0, stream>>>(b1, flag);
  hess_kernel<<<E_CNT / 256, 256, 0, stream>>>(U, state, conns, grads,
                                               vols, flag, out);
}

// Round 5
// 193.269 us; speedup vs baseline: 1.0065x; 1.0065x over previous
//
#include <hip/hip_runtime.h>

// MechanicsFunctionsMultiBlock: per-element Neo-Hookean energy Hessian (2D, NEN=3, NQP=1).
// Closed-form Hessian:
//   H[n,c,m,d] = vol * ( mu_eff * (c==d) * dot(G[n],G[m])
//                      + (mu_eff - lam*logJ) * P[n,d]*P[m,c]
//                      + lam * P[n,c]*P[m,d] )
// with F = I + gradU, P = G * F^{-1}, mu_eff = mu*(1 + 0.01*state).
//
// R5: flat-36 LDS staging with ds_{write,read}_b128 (element t at byte 144*t,
// always 16B-aligned; bank-group (9t+i)%8 spreads evenly), two-phase flush
// (18.4 KB LDS -> occupancy headroom), nontemporal float4 output stores,
// int4-vectorized flag scatter.

constexpr int E_CNT  = 800000;
constexpr int HALF_E = 400000;

typedef float v4f __attribute__((ext_vector_type(4)));

__global__ __launch_bounds__(256) void zero_flags_kernel(uint4* __restrict__ flag4) {
  int i = blockIdx.x * blockDim.x + threadIdx.x;
  if (i < E_CNT / 16) flag4[i] = make_uint4(0, 0, 0, 0);
}

__global__ __launch_bounds__(256) void mark_b1_kernel(
    const int4* __restrict__ b1, unsigned char* __restrict__ flag) {
  int i = blockIdx.x * blockDim.x + threadIdx.x;
  if (i < HALF_E / 4) {
    int4 v = b1[i];
    flag[v.x] = 1;  // block1: lam=2.0, mu=1.0
    flag[v.y] = 1;
    flag[v.z] = 1;
    flag[v.w] = 1;
  }
}

__global__ __launch_bounds__(256) void hess_kernel(
    const float* __restrict__ U, const float* __restrict__ state,
    const int* __restrict__ conns, const float* __restrict__ grads,
    const float* __restrict__ vols, const unsigned char* __restrict__ flag,
    float* __restrict__ out) {
  __shared__ float lds[128 * 36];  // 18432 B: two-phase staging buffer
  const int tid = threadIdx.x;
  const int e = blockIdx.x * 256 + tid;  // E = 3125*256 exactly, no tail

  const bool b  = flag[e] != 0;
  const float lam = b ? 2.0f : 1.0f;
  const float mu  = b ? 1.0f : 0.5f;

  const int n0 = conns[3 * e + 0];
  const int n1 = conns[3 * e + 1];
  const int n2 = conns[3 * e + 2];
  const float2 d0 = *(const float2*)(U + 2 * n0);
  const float2 d1 = *(const float2*)(U + 2 * n1);
  const float2 d2 = *(const float2*)(U + 2 * n2);
  const float2* gp = (const float2*)(grads + 6 * e);
  const float2 g0 = gp[0], g1 = gp[1], g2 = gp[2];

  // gradU[c][d] = sum_n D[n][c] * G[n][d]
  const float gu00 = d0.x * g0.x + d1.x * g1.x + d2.x * g2.x;
  const float gu01 = d0.x * g0.y + d1.x * g1.y + d2.x * g2.y;
  const float gu10 = d0.y * g0.x + d1.y * g1.x + d2.y * g2.x;
  const float gu11 = d0.y * g0.y + d1.y * g1.y + d2.y * g2.y;

  const float F00 = 1.0f + gu00, F01 = gu01, F10 = gu10, F11 = 1.0f + gu11;
  const float J    = F00 * F11 - F01 * F10;
  const float logJ = logf(J);
  const float rJ   = 1.0f / J;
  const float Fi00 =  F11 * rJ, Fi01 = -F01 * rJ;
  const float Fi10 = -F10 * rJ, Fi11 =  F00 * rJ;

  // P[n][c] = G[n][0]*Finv[0][c] + G[n][1]*Finv[1][c]
  float P[3][2];
  P[0][0] = g0.x * Fi00 + g0.y * Fi10;  P[0][1] = g0.x * Fi01 + g0.y * Fi11;
  P[1][0] = g1.x * Fi00 + g1.y * Fi10;  P[1][1] = g1.x * Fi01 + g1.y * Fi11;
  P[2][0] = g2.x * Fi00 + g2.y * Fi10;  P[2][1] = g2.x * Fi01 + g2.y * Fi11;

  const float gx[3] = {g0.x, g1.x, g2.x};
  const float gy[3] = {g0.y, g1.y, g2.y};

  const float mu_eff = mu * (1.0f + 0.01f * state[e]);
  const float c2     = mu_eff - lam * logJ;
  const float vol    = vols[e];

  // h packed as 9 float4s (flat index q = n*12 + c*6 + m*2 + d).
  v4f hq[9];
#pragma unroll
  for (int n = 0; n < 3; ++n) {
#pragma unroll
    for (int m = 0; m < 3; ++m) {
      const float dg = gx[n] * gx[m] + gy[n] * gy[m];
#pragma unroll
      for (int c = 0; c < 2; ++c) {
#pragma unroll
        for (int d = 0; d < 2; ++d) {
          float v = c2 * P[n][d] * P[m][c] + lam * P[n][c] * P[m][d];
          if (c == d) v += mu_eff * dg;
          const int q = n * 12 + c * 6 + m * 2 + d;
          hq[q >> 2][q & 3] = vol * v;
        }
      }
    }
  }

  // Two-phase flush: phase p stages elements [p*128, p*128+128) flat in LDS
  // (element t at byte 144*t -> 16B-aligned ds_write_b128), then the whole
  // block streams 1152 float4s (4608 floats) out coalesced + nontemporal.
  const int half = tid >> 7;  // wave-uniform: waves 0,1 vs 2,3
  float* const out_base = out + 36 * (size_t)(blockIdx.x * 256);
#pragma unroll
  for (int p = 0; p < 2; ++p) {
    if (p) __syncthreads();
    if (half == p) {
      float* hl = lds + (tid & 127) * 36;
#pragma unroll
      for (int i = 0; i < 9; ++i) *(v4f*)(hl + 4 * i) = hq[i];
    }
    __syncthreads();
    float* const ob = out_base + p * 4608;
#pragma unroll
    for (int r = 0; r < 4; ++r) {
      const int s = tid + r * 256;  // float4 slot
      v4f v = *(const v4f*)(lds + 4 * s);
      __builtin_nontemporal_store(v, (v4f*)(ob + 4 * s));
    }
    if (tid < 128) {  // wave-uniform tail: 1152 = 4*256 + 128
      const int s = tid + 1024;
      v4f v = *(const v4f*)(lds + 4 * s);
      __builtin_nontemporal_store(v, (v4f*)(ob + 4 * s));
    }
  }
}

extern "C" void kernel_launch(void* const* d_in, const int* in_sizes, int n_in,
                              void* d_out, int out_size, void* d_ws, size_t ws_size,
                              hipStream_t stream) {
  const float* U     = (const float*)d_in[0];
  // d_in[1] = coords   (unused by the Hessian)
  const float* state = (const float*)d_in[2];
  const int*   conns = (const int*)d_in[3];
  // d_in[4] = shapes   (unused by the Hessian)
  const float* grads = (const float*)d_in[5];
  const float* vols  = (const float*)d_in[6];
  // d_in[7] = blocks0  (flag defaults to 0)
  const int*   b1    = (const int*)d_in[8];
  float* out = (float*)d_out;
  unsigned char* flag = (unsigned char*)d_ws;  // E bytes of scratch

  zero_flags_kernel<<<(E_CNT / 16 + 255) / 256, 256, 0, stream>>>((uint4*)flag);
  mark_b1_kernel<<<(HALF_E / 4 + 255) / 256, 256, 0, stream>>>((const int4*)b1, flag);
  hess_kernel<<<E_CNT / 256, 256, 0, stream>>>(U, state, conns, grads,
                                               vols, flag, out);
}